// Round 1
// baseline (389.717 us; speedup 1.0000x reference)
//
#include <hip/hip_runtime.h>

typedef __bf16 bf16x8 __attribute__((ext_vector_type(8)));
typedef float  f32x4  __attribute__((ext_vector_type(4)));
typedef unsigned short u16;
typedef unsigned short us4 __attribute__((ext_vector_type(4)));

__device__ __forceinline__ u16 f2bf(float f) {
  __bf16 h = (__bf16)f;
  return __builtin_bit_cast(u16, h);
}

__device__ __forceinline__ void gload16(const void* g, void* l) {
  __builtin_amdgcn_global_load_lds(
      (const __attribute__((address_space(1))) unsigned int*)(g),
      (__attribute__((address_space(3))) unsigned int*)(l), 16, 0, 0);
}

// ---------------- GroupNorm: pass 1 (partial sums) ----------------
// grid (8 chunks, 32 groups, 4 batches), block 256
__global__ void gn_partial(const float* __restrict__ x, float* __restrict__ part) {
  const int chunk = blockIdx.x, g = blockIdx.y, b = blockIdx.z;
  const int tid = threadIdx.x;
  float s = 0.f, ss = 0.f;
  const float* xb = x + ((size_t)(b * 4096 + chunk * 512)) * 512 + g * 16;
  for (int i = tid; i < 2048; i += 256) {
    const int sp = i >> 2, c4 = (i & 3) << 2;
    const float4 v = *(const float4*)(xb + (size_t)sp * 512 + c4);
    s  += v.x + v.y + v.z + v.w;
    ss += v.x * v.x + v.y * v.y + v.z * v.z + v.w * v.w;
  }
  for (int m = 32; m; m >>= 1) { s += __shfl_xor(s, m); ss += __shfl_xor(ss, m); }
  __shared__ float red[8];
  const int w = tid >> 6;
  if ((tid & 63) == 0) { red[w * 2] = s; red[w * 2 + 1] = ss; }
  __syncthreads();
  if (tid == 0) {
    float S = 0.f, SS = 0.f;
    for (int i = 0; i < 4; ++i) { S += red[2 * i]; SS += red[2 * i + 1]; }
    const int idx = ((b * 32 + g) * 8 + chunk) * 2;
    part[idx] = S; part[idx + 1] = SS;
  }
}

// ---------------- GroupNorm: pass 2 (finalize) ----------------
__global__ void gn_finalize(const float* __restrict__ part, float* __restrict__ stats) {
  const int t = threadIdx.x;  // 128 = 4*32
  if (t < 128) {
    float S = 0.f, SS = 0.f;
    for (int i = 0; i < 8; ++i) { S += part[(t * 8 + i) * 2]; SS += part[(t * 8 + i) * 2 + 1]; }
    const float mean = S * (1.0f / 65536.0f);
    const float var  = SS * (1.0f / 65536.0f) - mean * mean;
    stats[t * 2] = mean;
    stats[t * 2 + 1] = rsqrtf(var + 1e-6f);
  }
}

// ---------------- GroupNorm: pass 3 (normalize + cast bf16) ----------------
__global__ void gn_apply(const float* __restrict__ x, const float* __restrict__ gamma,
                         const float* __restrict__ beta, const float* __restrict__ stats,
                         u16* __restrict__ h) {
  const size_t i = (size_t)blockIdx.x * 256 + threadIdx.x;  // 0..2097151
  const size_t e = i * 4;
  const int c = (int)(e & 511);
  const int b = (int)(e >> 21);          // e/(4096*512)
  const int g = c >> 4;
  const float mean = stats[(b * 32 + g) * 2];
  const float rstd = stats[(b * 32 + g) * 2 + 1];
  const float4 xv = *(const float4*)(x + e);
  const float4 gv = *(const float4*)(gamma + c);
  const float4 bv = *(const float4*)(beta + c);
  us4 hv;
  hv.x = f2bf((xv.x - mean) * rstd * gv.x + bv.x);
  hv.y = f2bf((xv.y - mean) * rstd * gv.y + bv.y);
  hv.z = f2bf((xv.z - mean) * rstd * gv.z + bv.z);
  hv.w = f2bf((xv.w - mean) * rstd * gv.w + bv.w);
  *(us4*)(h + e) = hv;
}

// ---------------- weight transpose + cast: wT[n][k] = bf16(w[k][n]) ----------------
__global__ void wcast_t(const float* __restrict__ w, u16* __restrict__ wT) {
  const int idx = blockIdx.x * 256 + threadIdx.x;  // 0..262143
  const int n = idx >> 9, k = idx & 511;
  wT[idx] = f2bf(w[k * 512 + n]);
}

// ---------------- bf16 GEMM: C[M,512] = A[M,512] @ Bt[n][k]^T, 128x128 tile ----------------
// EPI 0: bf16 out, (acc+bias)*scale       (q with scale, k with scale=1)
// EPI 1: bf16 out in V8 layout [B][N/8][C][8], acc+bias
// EPI 2: f32 out, acc+bias+resid          (o-projection + residual)
template <int EPI>
__global__ __launch_bounds__(256)
void gemm_bt(const u16* __restrict__ A, const u16* __restrict__ Bt,
             const float* __restrict__ bias, const float* __restrict__ resid,
             void* __restrict__ Cout, float scale) {
  const int tid = threadIdx.x;
  const int wid = tid >> 6, l = tid & 63;
  const int wr = wid >> 1, wc = wid & 1;
  const int l15 = l & 15, lq = l >> 4;
  const int brow = blockIdx.x * 128, bcol = blockIdx.y * 128;

  __shared__ u16 lA[2][4096];  // 128 x 32 bf16, chunk-XOR swizzled
  __shared__ u16 lB[2][4096];

  const f32x4 zero4 = {0.f, 0.f, 0.f, 0.f};
  f32x4 acc[4][4];
#pragma unroll
  for (int a = 0; a < 4; ++a)
#pragma unroll
    for (int bq_ = 0; bq_ < 4; ++bq_) acc[a][bq_] = zero4;

#define STAGE(buf, t)                                                            \
  {                                                                              \
    const int k0 = (t) * 32;                                                     \
    _Pragma("unroll")                                                            \
    for (int i = 0; i < 2; ++i) {                                                \
      const int cid = tid + i * 256;                                             \
      const int row = cid >> 2, cb = cid & 3;                                    \
      const int sc = (cb ^ (row & 3)) << 3;                                      \
      gload16(A + (size_t)(brow + row) * 512 + k0 + sc, &lA[buf][cid << 3]);     \
      gload16(Bt + (size_t)(bcol + row) * 512 + k0 + sc, &lB[buf][cid << 3]);    \
    }                                                                            \
  }

  STAGE(0, 0);
  asm volatile("s_waitcnt vmcnt(0)" ::: "memory");
  __syncthreads();
  int buf = 0;
  for (int t = 0; t < 16; ++t) {
    if (t < 15) STAGE(buf ^ 1, t + 1);
    bf16x8 af[4], bfv[4];
#pragma unroll
    for (int f = 0; f < 4; ++f) {
      const int ra = wr * 64 + f * 16 + l15;
      af[f] = *(const bf16x8*)(&lA[buf][(ra << 5) + ((lq ^ (ra & 3)) << 3)]);
      const int rb = wc * 64 + f * 16 + l15;
      bfv[f] = *(const bf16x8*)(&lB[buf][(rb << 5) + ((lq ^ (rb & 3)) << 3)]);
    }
#pragma unroll
    for (int fa = 0; fa < 4; ++fa)
#pragma unroll
      for (int fb = 0; fb < 4; ++fb)
        acc[fa][fb] = __builtin_amdgcn_mfma_f32_16x16x32_bf16(af[fa], bfv[fb], acc[fa][fb], 0, 0, 0);
    asm volatile("s_waitcnt vmcnt(0)" ::: "memory");
    __syncthreads();
    buf ^= 1;
  }
#undef STAGE

#pragma unroll
  for (int fa = 0; fa < 4; ++fa) {
#pragma unroll
    for (int fb = 0; fb < 4; ++fb) {
      const int col = bcol + wc * 64 + fb * 16 + l15;
      const float bv = bias[col];
#pragma unroll
      for (int i = 0; i < 4; ++i) {
        const int row = brow + wr * 64 + fa * 16 + lq * 4 + i;
        const float v = acc[fa][fb][i] + bv;
        if (EPI == 0) {
          ((u16*)Cout)[(size_t)row * 512 + col] = f2bf(v * scale);
        } else if (EPI == 1) {
          const int bb = row >> 12, n = row & 4095;
          ((u16*)Cout)[((size_t)(bb * 512 + (n >> 3))) * 4096 + (size_t)col * 8 + (n & 7)] = f2bf(v);
        } else {
          const size_t idx = (size_t)row * 512 + col;
          ((float*)Cout)[idx] = v + resid[idx];
        }
      }
    }
  }
}

// ---------------- flash attention: BQ=64, BKV=32, D=512, 8 waves ----------------
// grid (64 q-blocks, 4 batches), block 512
__global__ __launch_bounds__(512)
void attn_kernel(const u16* __restrict__ Q, const u16* __restrict__ K,
                 const u16* __restrict__ V8, u16* __restrict__ Oo) {
  const int b = blockIdx.y;
  const int qb = blockIdx.x;
  const int tid = threadIdx.x;
  const int wid = tid >> 6;
  const int l = tid & 63;
  const int r = wid & 3;    // S/O row-group (16 rows)
  const int cg = wid >> 2;  // S col-group (16 cols) / O col-group (256 cols)
  const int l15 = l & 15;
  const int lq = l >> 4;

  __shared__ u16 kvb[16384];      // 32 KB union: K-tile [32][512] swizzled | V8-tile [4][512][8]
  __shared__ float Sb[64 * 36];   // scores, f32
  __shared__ u16 Pb[64 * 40];     // probabilities, bf16
  __shared__ float mrow[64], lrow[64], arow[64];
  __shared__ int flag;

  // Q fragments in registers: rows r*16..+16, full K=512
  bf16x8 qf[16];
  {
    const u16* qp = Q + ((size_t)(b * 4096 + qb * 64 + r * 16 + l15)) * 512 + lq * 8;
#pragma unroll
    for (int kk = 0; kk < 16; ++kk) qf[kk] = *(const bf16x8*)(qp + kk * 32);
  }
  const f32x4 zero4 = {0.f, 0.f, 0.f, 0.f};
  f32x4 o[16];
#pragma unroll
  for (int f = 0; f < 16; ++f) o[f] = zero4;

  if (tid < 64) { mrow[tid] = -__builtin_inff(); lrow[tid] = 0.f; arow[tid] = 1.f; }
  if (tid == 0) flag = 0;
  __syncthreads();

  const u16* Kb = K + (size_t)b * 4096 * 512;
  const u16* Vb = V8 + (size_t)b * 4096 * 512;

  for (int t = 0; t < 128; ++t) {
    const int n0 = t * 32;
    // ---- stage K tile [32][512] with (n&7) chunk-XOR swizzle (pre-swizzled source) ----
#pragma unroll
    for (int i = 0; i < 4; ++i) {
      const int cid = tid + i * 512;
      const int ob = cid << 4;                       // byte offset in tile
      const int n = ob >> 10;                        // kv row 0..31
      const int cb = (ob & 1023) ^ ((n & 7) << 4);   // swizzled in-row byte
      gload16(Kb + (size_t)(n0 + n) * 512 + (cb >> 1), (u16*)kvb + (cid << 3));
    }
    asm volatile("s_waitcnt vmcnt(0)" ::: "memory");
    __syncthreads();
    if (tid == 0) flag = 0;

    // ---- S = Q K^T (this wave: rows r*16..+16, cols cg*16..+16) ----
    f32x4 sacc = zero4;
    {
      const int n = cg * 16 + l15;
      const int swz = (n & 7) << 4;
      const char* kb = (const char*)(kvb + (n << 9));
#pragma unroll
      for (int kk = 0; kk < 16; ++kk) {
        const bf16x8 bfr = *(const bf16x8*)(kb + ((kk * 64 + (lq << 4)) ^ swz));
        sacc = __builtin_amdgcn_mfma_f32_16x16x32_bf16(qf[kk], bfr, sacc, 0, 0, 0);
      }
    }
    {
      const int col = cg * 16 + l15;
      const int rb = r * 16 + lq * 4;
#pragma unroll
      for (int i = 0; i < 4; ++i) Sb[(rb + i) * 36 + col] = sacc[i];
    }
    __syncthreads();

    // ---- issue V staging now (hides under softmax); blocked layout -> linear copy ----
    {
      const u16* vs = Vb + (size_t)n0 * 512;
#pragma unroll
      for (int i = 0; i < 4; ++i) {
        const int cid = tid + i * 512;
        gload16(vs + (cid << 3), (u16*)kvb + (cid << 3));
      }
    }

    // ---- online softmax with defer-max (THR=8) ----
    {
      const int row = tid >> 3, i8 = tid & 7;
      const f32x4 sv = *(const f32x4*)(Sb + row * 36 + i8 * 4);
      float tmax = fmaxf(fmaxf(sv[0], sv[1]), fmaxf(sv[2], sv[3]));
#pragma unroll
      for (int m = 1; m < 8; m <<= 1) tmax = fmaxf(tmax, __shfl_xor(tmax, m, 8));
      const float mo = mrow[row];
      const bool need = tmax > mo + 8.0f;
      const float mn = need ? tmax : mo;
      const float al = need ? __expf(mo - mn) : 1.0f;
      const float p0 = __expf(sv[0] - mn), p1 = __expf(sv[1] - mn);
      const float p2 = __expf(sv[2] - mn), p3 = __expf(sv[3] - mn);
      float ps = p0 + p1 + p2 + p3;
#pragma unroll
      for (int m = 1; m < 8; m <<= 1) ps += __shfl_xor(ps, m, 8);
      u16* pp = Pb + row * 40 + i8 * 4;
      pp[0] = f2bf(p0); pp[1] = f2bf(p1); pp[2] = f2bf(p2); pp[3] = f2bf(p3);
      if (i8 == 0) {
        lrow[row] = lrow[row] * al + ps;
        if (need) {
          mrow[row] = mn;
          arow[row] = al;
          if (mo > -1e30f) atomicOr(&flag, 1);
        } else {
          arow[row] = 1.0f;
        }
      }
    }
    asm volatile("s_waitcnt vmcnt(0)" ::: "memory");
    __syncthreads();

    // ---- rescale O (rare, thanks to defer-max) ----
    if (flag) {
      const int rb = r * 16 + lq * 4;
      const float a0 = arow[rb], a1 = arow[rb + 1], a2 = arow[rb + 2], a3 = arow[rb + 3];
#pragma unroll
      for (int f = 0; f < 16; ++f) {
        o[f][0] *= a0; o[f][1] *= a1; o[f][2] *= a2; o[f][3] *= a3;
      }
    }
    // ---- O += P @ V ----
    {
      const bf16x8 pa = *(const bf16x8*)((const char*)Pb + (r * 16 + l15) * 80 + (lq << 4));
      const char* vbase = (const char*)kvb + (lq << 13);  // nb*8192
#pragma unroll
      for (int f = 0; f < 16; ++f) {
        const bf16x8 vf = *(const bf16x8*)(vbase + (cg * 256 + f * 16 + l15) * 16);
        o[f] = __builtin_amdgcn_mfma_f32_16x16x32_bf16(pa, vf, o[f], 0, 0, 0);
      }
    }
    __syncthreads();
  }

  // ---- epilogue: O /= l, cast bf16, store ----
  {
    const int rb = r * 16 + lq * 4;
    float li[4];
#pragma unroll
    for (int i = 0; i < 4; ++i) li[i] = 1.0f / lrow[rb + i];
    u16* ob = Oo + ((size_t)(b * 4096 + qb * 64)) * 512;
#pragma unroll
    for (int f = 0; f < 16; ++f) {
      const int col = cg * 256 + f * 16 + l15;
#pragma unroll
      for (int i = 0; i < 4; ++i) ob[(size_t)(rb + i) * 512 + col] = f2bf(o[f][i] * li[i]);
    }
  }
}

extern "C" void kernel_launch(void* const* d_in, const int* in_sizes, int n_in,
                              void* d_out, int out_size, void* d_ws, size_t ws_size,
                              hipStream_t stream) {
  const float* x     = (const float*)d_in[0];
  const float* gamma = (const float*)d_in[1];
  const float* beta  = (const float*)d_in[2];
  const float* wq    = (const float*)d_in[3];
  const float* bq    = (const float*)d_in[4];
  const float* wk    = (const float*)d_in[5];
  const float* bk    = (const float*)d_in[6];
  const float* wv    = (const float*)d_in[7];
  const float* bv    = (const float*)d_in[8];
  const float* wo    = (const float*)d_in[9];
  const float* bo    = (const float*)d_in[10];
  float* out = (float*)d_out;

  // workspace layout (requires ~86 MB)
  char* ws = (char*)d_ws;
  const size_t SZ = (size_t)16384 * 512;  // elements per [B*N, C] tensor
  u16* h    = (u16*)(ws);                 // 16 MB bf16
  u16* q    = (u16*)(ws + SZ * 2);        // 16 MB (pre-scaled by C^-0.5)
  u16* k    = (u16*)(ws + SZ * 4);        // 16 MB
  u16* v8   = (u16*)(ws + SZ * 6);        // 16 MB, layout [B][N/8][C][8]
  u16* aout = (u16*)(ws + SZ * 8);        // 16 MB
  u16* wT   = (u16*)(ws + SZ * 10);       // 4 x 512KB bf16 transposed weights
  float* part  = (float*)(ws + SZ * 10 + 4 * 262144 * 2);
  float* stats = part + 2048;

  gn_partial<<<dim3(8, 32, 4), 256, 0, stream>>>(x, part);
  gn_finalize<<<1, 128, 0, stream>>>(part, stats);
  gn_apply<<<8192, 256, 0, stream>>>(x, gamma, beta, stats, h);

  wcast_t<<<1024, 256, 0, stream>>>(wq, wT);
  wcast_t<<<1024, 256, 0, stream>>>(wk, wT + 262144);
  wcast_t<<<1024, 256, 0, stream>>>(wv, wT + 2 * 262144);
  wcast_t<<<1024, 256, 0, stream>>>(wo, wT + 3 * 262144);

  const float qs = 0.044194173824159216f;  // 512^-0.5
  gemm_bt<0><<<dim3(128, 4), 256, 0, stream>>>(h, wT,               bq, nullptr, q,   qs);
  gemm_bt<0><<<dim3(128, 4), 256, 0, stream>>>(h, wT + 262144,      bk, nullptr, k,   1.0f);
  gemm_bt<1><<<dim3(128, 4), 256, 0, stream>>>(h, wT + 2 * 262144,  bv, nullptr, v8,  1.0f);

  attn_kernel<<<dim3(64, 4), 512, 0, stream>>>(q, k, v8, aout);

  gemm_bt<2><<<dim3(128, 4), 256, 0, stream>>>(aout, wT + 3 * 262144, bo, x, out, 1.0f);
}